// Round 6
// baseline (465.700 us; speedup 1.0000x reference)
//
#include <hip/hip_runtime.h>
#include <hip/hip_bf16.h>

typedef int v4i __attribute__((ext_vector_type(4)));

// ---------------------------------------------------------------------------
// Kernel 0: pack int32-widened weight -> int8 bytes
// ---------------------------------------------------------------------------
__global__ __launch_bounds__(256) void pack_w_kernel(const int* __restrict__ w,
                                                     int* __restrict__ wq,
                                                     int n4) {
    int i = blockIdx.x * 256 + threadIdx.x;
    if (i < n4) {
        const int4 v = reinterpret_cast<const int4*>(w)[i];
        wq[i] = (v.x & 0xFF) | ((v.y & 0xFF) << 8) |
                ((v.z & 0xFF) << 16) | ((v.w & 0xFF) << 24);
    }
}

// ---------------------------------------------------------------------------
// Kernel 1: per-row absmax quantize fp32 -> int8 (packed), store a_s per row
// One block (256 threads) per row of K floats.
// ---------------------------------------------------------------------------
__global__ __launch_bounds__(256) void quant_kernel(const float* __restrict__ x,
                                                    int* __restrict__ aq,
                                                    float* __restrict__ a_s,
                                                    int K) {
    const int row = blockIdx.x;
    const float4* xr = reinterpret_cast<const float4*>(x + (size_t)row * K);
    const int K4 = K >> 2;

    float m = 0.f;
    for (int i = threadIdx.x; i < K4; i += 256) {
        float4 v = xr[i];
        m = fmaxf(m, fmaxf(fmaxf(fabsf(v.x), fabsf(v.y)),
                           fmaxf(fabsf(v.z), fabsf(v.w))));
    }
#pragma unroll
    for (int off = 32; off; off >>= 1) m = fmaxf(m, __shfl_xor(m, off));

    __shared__ float red[4];
    if ((threadIdx.x & 63) == 0) red[threadIdx.x >> 6] = m;
    __syncthreads();
    m = fmaxf(fmaxf(red[0], red[1]), fmaxf(red[2], red[3]));

    const float as = (m == 0.f) ? 1.f : (m / 127.0f);   // match ref rounding path
    if (threadIdx.x == 0) a_s[row] = as;

    int* aqr = aq + (size_t)row * K4;
    for (int i = threadIdx.x; i < K4; i += 256) {
        float4 v = xr[i];   // L1/L2 hit (row = 16 KiB)
        int q0 = (int)rintf(v.x / as);  // IEEE div + RNE matches jnp.round(x/a_s)
        int q1 = (int)rintf(v.y / as);
        int q2 = (int)rintf(v.z / as);
        int q3 = (int)rintf(v.w / as);
        q0 = min(127, max(-128, q0));
        q1 = min(127, max(-128, q1));
        q2 = min(127, max(-128, q2));
        q3 = min(127, max(-128, q3));
        aqr[i] = (q0 & 0xFF) | ((q1 & 0xFF) << 8) |
                 ((q2 & 0xFF) << 16) | ((q3 & 0xFF) << 24);
    }
}

// ---------------------------------------------------------------------------
// Kernel 2: int8 GEMM  C[M,N] = Aq[M,K] . Wq[N,K]^T  with fp32 dequant epilogue
// m97 structure: 128x128 tile, BK=64, 4 waves (2x2), global_load_lds staging.
// ---------------------------------------------------------------------------
__global__ __launch_bounds__(256) void gemm_i8_kernel(
    const signed char* __restrict__ Aq,   // [M,K]
    const signed char* __restrict__ Wq,   // [N,K]
    const float* __restrict__ a_s,        // [M]
    const float* __restrict__ w_s,        // [N]
    float* __restrict__ out,              // [M,N]
    int M, int N, int K) {

    __shared__ __align__(16) signed char As[128 * 64];
    __shared__ __align__(16) signed char Bs[128 * 64];

    const int t    = threadIdx.x;
    const int lane = t & 63;
    const int wave = t >> 6;
    const int wr   = wave >> 1;   // 0..1  (M direction)
    const int wc   = wave & 1;    // 0..1  (N direction)

    const int tile_m = blockIdx.y * 128;
    const int tile_n = blockIdx.x * 128;

    v4i acc[4][4];
#pragma unroll
    for (int m = 0; m < 4; ++m)
#pragma unroll
        for (int n = 0; n < 4; ++n) acc[m][n] = (v4i){0, 0, 0, 0};

    // staging: thread t loads 16 bytes at row t/4, col (t%4)*16 (issue 0: rows 0..63)
    const int srow = t >> 2;
    const int scol = (t & 3) * 16;
    const signed char* gA = Aq + (size_t)(tile_m + srow) * K + scol;
    const signed char* gB = Wq + (size_t)(tile_n + srow) * K + scol;

    signed char* lA0 = &As[t * 16];
    signed char* lA1 = &As[4096 + t * 16];
    signed char* lB0 = &Bs[t * 16];
    signed char* lB1 = &Bs[4096 + t * 16];

    // fragment read offsets (A: row l&15, k (l>>4)*16 — 16x16x64 i8 layout)
    const int fr = lane & 15;
    const int fq = lane >> 4;
    const int a_off = (wr * 64 + fr) * 64 + fq * 16;
    const int b_off = (wc * 64 + fr) * 64 + fq * 16;

    const size_t rowstep = (size_t)64 * K;
    const int nk = K >> 6;
    for (int kt = 0; kt < nk; ++kt) {
        __syncthreads();
        __builtin_amdgcn_global_load_lds(
            (const __attribute__((address_space(1))) void*)gA,
            (__attribute__((address_space(3))) void*)lA0, 16, 0, 0);
        __builtin_amdgcn_global_load_lds(
            (const __attribute__((address_space(1))) void*)(gA + rowstep),
            (__attribute__((address_space(3))) void*)lA1, 16, 0, 0);
        __builtin_amdgcn_global_load_lds(
            (const __attribute__((address_space(1))) void*)gB,
            (__attribute__((address_space(3))) void*)lB0, 16, 0, 0);
        __builtin_amdgcn_global_load_lds(
            (const __attribute__((address_space(1))) void*)(gB + rowstep),
            (__attribute__((address_space(3))) void*)lB1, 16, 0, 0);
        gA += 64;
        gB += 64;
        __syncthreads();

        v4i af[4], bf[4];
#pragma unroll
        for (int m = 0; m < 4; ++m)
            af[m] = *reinterpret_cast<const v4i*>(As + a_off + m * 16 * 64);
#pragma unroll
        for (int n = 0; n < 4; ++n)
            bf[n] = *reinterpret_cast<const v4i*>(Bs + b_off + n * 16 * 64);

#pragma unroll
        for (int m = 0; m < 4; ++m)
#pragma unroll
            for (int n = 0; n < 4; ++n)
                acc[m][n] = __builtin_amdgcn_mfma_i32_16x16x64_i8(
                    af[m], bf[n], acc[m][n], 0, 0, 0);
    }

    // epilogue: C/D 16x16 layout col=lane&15, row=(lane>>4)*4+reg (m89-verified)
#pragma unroll
    for (int n = 0; n < 4; ++n) {
        const int gcol = tile_n + wc * 64 + n * 16 + fr;
        const float ws = w_s[gcol];
#pragma unroll
        for (int m = 0; m < 4; ++m) {
            const int rbase = tile_m + wr * 64 + m * 16 + fq * 4;
#pragma unroll
            for (int j = 0; j < 4; ++j) {
                const int grow = rbase + j;
                out[(size_t)grow * N + gcol] =
                    (float)acc[m][n][j] * a_s[grow] * ws;
            }
        }
    }
}

// ---------------------------------------------------------------------------
extern "C" void kernel_launch(void* const* d_in, const int* in_sizes, int n_in,
                              void* d_out, int out_size, void* d_ws, size_t ws_size,
                              hipStream_t stream) {
    const float* x      = (const float*)d_in[0];
    const int*   w      = (const int*)d_in[1];      // int8 widened to int32
    const float* wscale = (const float*)d_in[2];

    const int N = in_sizes[2];            // OUT
    const int K = in_sizes[1] / N;        // IN
    const int M = in_sizes[0] / K;        // B*S

    signed char* aq = (signed char*)d_ws;                       // M*K int8
    signed char* wq = aq + (size_t)M * K;                       // N*K int8
    float* as_buf   = (float*)(wq + (size_t)N * K);             // M floats

    const int n4 = (N * K) >> 2;
    pack_w_kernel<<<(n4 + 255) / 256, 256, 0, stream>>>(w, (int*)wq, n4);
    quant_kernel<<<M, 256, 0, stream>>>(x, (int*)aq, as_buf, K);

    dim3 grid(N / 128, M / 128);
    gemm_i8_kernel<<<grid, 256, 0, stream>>>(aq, wq, as_buf, wscale,
                                             (float*)d_out, M, N, K);
}